// Round 4
// baseline (2546.420 us; speedup 1.0000x reference)
//
#include <hip/hip_runtime.h>

#define C 16
#define TAPS 27
#define NCONV 17

// ---- weight transpose: W[l][co][ci][tap] -> Wt[l][tap][ci][co] ----
__global__ void transpose_w_kernel(const float* __restrict__ W, float* __restrict__ Wt) {
    int i = blockIdx.x * blockDim.x + threadIdx.x;
    const int total = NCONV * TAPS * C * C;
    if (i >= total) return;
    int co = i & 15;
    int ci = (i >> 4) & 15;
    int rest = i >> 8;
    int tap = rest % TAPS;
    int l = rest / TAPS;
    Wt[i] = W[(((long)l * C + co) * C + ci) * TAPS + tap];
}

// ---- x: NCDHW -> NDHWC ----
__global__ void transpose_in_kernel(const float* __restrict__ x, float* __restrict__ xt, int n) {
    int v = blockIdx.x * blockDim.x + threadIdx.x;
    if (v >= n) return;
    float a[C];
#pragma unroll
    for (int ci = 0; ci < C; ci++) a[ci] = x[(long)ci * n + v];
    float4* dp = reinterpret_cast<float4*>(xt + (long)v * C);
    dp[0] = make_float4(a[0], a[1], a[2], a[3]);
    dp[1] = make_float4(a[4], a[5], a[6], a[7]);
    dp[2] = make_float4(a[8], a[9], a[10], a[11]);
    dp[3] = make_float4(a[12], a[13], a[14], a[15]);
}

// ---- NDHWC -> NCDHW (stage outputs into d_out) ----
__global__ void to_ncdhw_kernel(const float* __restrict__ src, float* __restrict__ dst, int n) {
    int v = blockIdx.x * blockDim.x + threadIdx.x;
    if (v >= n) return;
    const float4* sp = reinterpret_cast<const float4*>(src + (long)v * C);
    float4 q0 = sp[0], q1 = sp[1], q2 = sp[2], q3 = sp[3];
    float a[C] = {q0.x, q0.y, q0.z, q0.w, q1.x, q1.y, q1.z, q1.w,
                  q2.x, q2.y, q2.z, q2.w, q3.x, q3.y, q3.z, q3.w};
#pragma unroll
    for (int co = 0; co < C; co++) dst[(long)co * n + v] = a[co];
}

// ---- ordered compaction: counts -> scan -> scatter ----
__global__ void count_kernel(const int* __restrict__ mi, int* __restrict__ counts, int n) {
    int i = blockIdx.x * 256 + threadIdx.x;
    int act = (i < n) && (mi[i] == 0);
    unsigned long long b = __ballot(act);
    __shared__ int wsum[4];
    int wid = threadIdx.x >> 6, lane = threadIdx.x & 63;
    if (lane == 0) wsum[wid] = __popcll(b);
    __syncthreads();
    if (threadIdx.x == 0) counts[blockIdx.x] = wsum[0] + wsum[1] + wsum[2] + wsum[3];
}

__global__ void scan_kernel(const int* __restrict__ counts, int* __restrict__ offsets,
                            int* __restrict__ nact, int nb) {
    __shared__ int s[256];
    int t = threadIdx.x;
    const int CH = (nb + 255) / 256;
    int base = t * CH, sum = 0;
    for (int j = 0; j < CH; j++)
        if (base + j < nb) sum += counts[base + j];
    s[t] = sum;
    __syncthreads();
    for (int off = 1; off < 256; off <<= 1) {
        int v = (t >= off) ? s[t - off] : 0;
        __syncthreads();
        s[t] += v;
        __syncthreads();
    }
    int run = s[t] - sum;  // exclusive base
    for (int j = 0; j < CH; j++) {
        if (base + j < nb) {
            offsets[base + j] = run;
            run += counts[base + j];
        }
    }
    if (t == 255) *nact = s[255];
}

__global__ void scatter_kernel(const int* __restrict__ mi, const int* __restrict__ offsets,
                               int* __restrict__ list, int n, int cap) {
    int i = blockIdx.x * 256 + threadIdx.x;
    int act = (i < n) && (mi[i] == 0);
    unsigned long long b = __ballot(act);
    __shared__ int wsum[4];
    int wid = threadIdx.x >> 6, lane = threadIdx.x & 63;
    if (lane == 0) wsum[wid] = __popcll(b);
    __syncthreads();
    int wbase = 0;
    for (int w = 0; w < wid; w++) wbase += wsum[w];
    int prefix = __popcll(b & ((1ull << lane) - 1));
    if (act) {
        int pos = offsets[blockIdx.x] + wbase + prefix;
        if (pos < cap) list[pos] = i;
    }
}

// ---- mask maxpool (2x2x2 stride, 3^3 window) ----
template <bool FROM_INT>
__global__ void pool_mask_kernel(const int* __restrict__ mi, const float* __restrict__ mf,
                                 float* __restrict__ mout, int Din, int Dout) {
    int i = blockIdx.x * blockDim.x + threadIdx.x;
    int n = Dout * Dout * Dout;
    if (i >= n) return;
    int x = i % Dout, y = (i / Dout) % Dout, z = i / (Dout * Dout);
    float v = 0.f;
    for (int kz = 0; kz < 3; kz++) {
        int zz = 2 * z - 1 + kz;
        if (zz < 0 || zz >= Din) continue;
        for (int ky = 0; ky < 3; ky++) {
            int yy = 2 * y - 1 + ky;
            if (yy < 0 || yy >= Din) continue;
            for (int kx = 0; kx < 3; kx++) {
                int xx = 2 * x - 1 + kx;
                if (xx < 0 || xx >= Din) continue;
                long idx = ((long)zz * Din + yy) * Din + xx;
                float mv = FROM_INT ? ((mi[idx] == 0) ? 1.f : 0.f) : mf[idx];
                v = fmaxf(v, mv);
            }
        }
    }
    mout[i] = v;
}

// ---- conv in NDHWC; COPT output channels per thread ----
template <int STRIDE, bool SPARSE, int COPT>
__global__ __launch_bounds__(256) void conv_kernel(
    const float* __restrict__ in, float* __restrict__ out,
    const float* __restrict__ mask, const int* __restrict__ list,
    const int* __restrict__ nact, const float* __restrict__ Wt,
    const float* __restrict__ bs, const float* __restrict__ bb,
    int Din, int Dout) {
    constexpr int NCOG = C / COPT;
    constexpr int VPB = 256 / NCOG;  // voxels per block
    int n = Dout * Dout * Dout;
    int nv = SPARSE ? *nact : n;
    if (SPARSE && nv > 131072) nv = 131072;
    if (blockIdx.x * VPB >= nv) return;  // uniform early exit

    __shared__ float wl[TAPS * C * C];
    __shared__ float sc[C], bi[C];
    int tid = threadIdx.x;
    for (int idx = tid; idx < TAPS * C * C; idx += 256) wl[idx] = Wt[idx];
    if (tid < C) { sc[tid] = bs[tid]; bi[tid] = bb[tid]; }
    __syncthreads();

    int gid = blockIdx.x * 256 + tid;
    int s = gid / NCOG;
    int h = gid % NCOG;
    bool val = s < nv;
    int v = 0;
    if (val) v = SPARSE ? list[s] : s;
    int x = v % Dout, y = (v / Dout) % Dout, z = v / (Dout * Dout);
    float mk = SPARSE ? 1.f : (val ? mask[v] : 0.f);

    float acc[COPT];
#pragma unroll
    for (int j = 0; j < COPT; j++) acc[j] = 0.f;

    for (int kz = 0; kz < 3; kz++) {
        int zz = STRIDE * z - 1 + kz;
        for (int ky = 0; ky < 3; ky++) {
            int yy = STRIDE * y - 1 + ky;
#pragma unroll
            for (int kx = 0; kx < 3; kx++) {
                int xx = STRIDE * x - 1 + kx;
                bool ok = ((unsigned)zz < (unsigned)Din) && ((unsigned)yy < (unsigned)Din) &&
                          ((unsigned)xx < (unsigned)Din);
                long b = ok ? (((long)zz * Din + yy) * Din + xx) : 0;
                const float4* ip = reinterpret_cast<const float4*>(in + b * C);
                float4 q0 = ip[0], q1 = ip[1], q2 = ip[2], q3 = ip[3];
                const float4 z4 = make_float4(0.f, 0.f, 0.f, 0.f);
                if (!ok) { q0 = z4; q1 = z4; q2 = z4; q3 = z4; }
                float av[C] = {q0.x, q0.y, q0.z, q0.w, q1.x, q1.y, q1.z, q1.w,
                               q2.x, q2.y, q2.z, q2.w, q3.x, q3.y, q3.z, q3.w};
                const float* wt = &wl[((kz * 3 + ky) * 3 + kx) * C * C + h * COPT];
#pragma unroll
                for (int ci = 0; ci < C; ci++) {
                    float a = av[ci];
                    const float* wr = wt + ci * C;
#pragma unroll
                    for (int j = 0; j < COPT; j++) acc[j] += a * wr[j];
                }
            }
        }
    }
    float r[COPT];
#pragma unroll
    for (int j = 0; j < COPT; j++) {
        int co = h * COPT + j;
        r[j] = fmaxf(acc[j] * sc[co] + bi[co], 0.f) * mk;
    }
    if (val) {
        float* op = out + (long)v * C + h * COPT;
        if (COPT == 8) {
            float4* o4 = reinterpret_cast<float4*>(op);
            o4[0] = make_float4(r[0], r[1], r[2], r[3]);
            o4[1] = make_float4(r[4], r[5], r[6], r[7]);
        } else {
            float4* o4 = reinterpret_cast<float4*>(op);
            o4[0] = make_float4(r[0], r[1], r[2], r[3]);
        }
    }
}

extern "C" void kernel_launch(void* const* d_in, const int* in_sizes, int n_in,
                              void* d_out, int out_size, void* d_ws, size_t ws_size,
                              hipStream_t stream) {
    const float* x = (const float*)d_in[0];
    const int* mask_idx = (const int*)d_in[1];
    const float* W = (const float*)d_in[2];
    const float* bs = (const float*)d_in[3];
    const float* bb = (const float*)d_in[4];
    float* out = (float*)d_out;
    float* ws = (float*)d_ws;

    const int n96 = 96 * 96 * 96;  // 884736
    const int n48 = 48 * 48 * 48;  // 110592
    const int n24 = 24 * 24 * 24;  // 13824
    const int n12 = 12 * 12 * 12;  // 1728
    const int n6 = 6 * 6 * 6;      // 216
    const int NB = (n96 + 255) / 256;  // 3456
    const int LISTCAP = 262144;

    float* P0 = ws;                    // xt, then ping-pong
    float* P1 = P0 + (long)C * n96;    // ping-pong (pre-zeroed for sparse scatter)
    float* m48 = P1 + (long)C * n96;
    float* m24 = m48 + n48;
    float* m12 = m24 + n24;
    float* m6 = m12 + n12;
    float* Wt = m6 + n6;
    int* list = (int*)(Wt + (long)NCONV * TAPS * C * C);
    int* counts = list + LISTCAP;
    int* offsets = counts + NB;
    int* nact = offsets + NB;

    const int BS = 256;
    auto blk = [&](long t) { return dim3((unsigned)((t + BS - 1) / BS)); };

    hipMemsetAsync(P1, 0, (long)C * n96 * sizeof(float), stream);
    hipLaunchKernelGGL(transpose_w_kernel, blk(NCONV * TAPS * C * C), dim3(BS), 0, stream, W, Wt);
    hipLaunchKernelGGL(transpose_in_kernel, blk(n96), dim3(BS), 0, stream, x, P0, n96);
    hipLaunchKernelGGL(count_kernel, dim3(NB), dim3(BS), 0, stream, mask_idx, counts, n96);
    hipLaunchKernelGGL(scan_kernel, dim3(1), dim3(BS), 0, stream, counts, offsets, nact, NB);
    hipLaunchKernelGGL(scatter_kernel, dim3(NB), dim3(BS), 0, stream, mask_idx, offsets, list,
                       n96, LISTCAP);

    auto sconv = [&](const float* in, float* op, int layer) {
        hipLaunchKernelGGL((conv_kernel<1, true, 8>), dim3(1024), dim3(BS), 0, stream,
                           in, op, (const float*)nullptr, list, nact,
                           Wt + (long)layer * TAPS * C * C, bs + layer * C, bb + layer * C, 96, 96);
    };
    auto subm = [&](const float* in, float* op, const float* m, int layer, int D, bool small) {
        int n = D * D * D;
        if (!small)
            hipLaunchKernelGGL((conv_kernel<1, false, 8>), blk((long)n * 2), dim3(BS), 0, stream,
                               in, op, m, list, nact, Wt + (long)layer * TAPS * C * C,
                               bs + layer * C, bb + layer * C, D, D);
        else
            hipLaunchKernelGGL((conv_kernel<1, false, 4>), blk((long)n * 4), dim3(BS), 0, stream,
                               in, op, m, list, nact, Wt + (long)layer * TAPS * C * C,
                               bs + layer * C, bb + layer * C, D, D);
    };
    auto down = [&](const float* in, float* op, const float* m, int layer, int Dout, bool small) {
        int n = Dout * Dout * Dout;
        if (!small)
            hipLaunchKernelGGL((conv_kernel<2, false, 8>), blk((long)n * 2), dim3(BS), 0, stream,
                               in, op, m, list, nact, Wt + (long)layer * TAPS * C * C,
                               bs + layer * C, bb + layer * C, 2 * Dout, Dout);
        else
            hipLaunchKernelGGL((conv_kernel<2, false, 4>), blk((long)n * 4), dim3(BS), 0, stream,
                               in, op, m, list, nact, Wt + (long)layer * TAPS * C * C,
                               bs + layer * C, bb + layer * C, 2 * Dout, Dout);
    };

    // masks
    hipLaunchKernelGGL((pool_mask_kernel<true>), blk(n48), dim3(BS), 0, stream,
                       mask_idx, (const float*)nullptr, m48, 96, 48);
    hipLaunchKernelGGL((pool_mask_kernel<false>), blk(n24), dim3(BS), 0, stream,
                       (const int*)nullptr, m48, m24, 48, 24);
    hipLaunchKernelGGL((pool_mask_kernel<false>), blk(n12), dim3(BS), 0, stream,
                       (const int*)nullptr, m24, m12, 24, 12);
    hipLaunchKernelGGL((pool_mask_kernel<false>), blk(n6), dim3(BS), 0, stream,
                       (const int*)nullptr, m12, m6, 12, 6);

    // Stage @96 (sparse). L0: P0(xt) -> P1 (zeroed). L1: P1 -> P0 (inactive already 0).
    sconv(P0, P1, 0);
    sconv(P1, P0, 1);
    // 48 level (dense, ~94% mask)
    down(P0, P1, m48, 2, 48, false);
    subm(P1, P0, m48, 3, 48, false);
    subm(P0, P1, m48, 4, 48, false);  // net1 in P1
    hipLaunchKernelGGL(to_ncdhw_kernel, blk(n48), dim3(BS), 0, stream, P1, out, n48);
    // 24 level
    down(P1, P0, m24, 5, 24, true);
    subm(P0, P1, m24, 6, 24, true);
    subm(P1, P0, m24, 7, 24, true);
    subm(P0, P1, m24, 8, 24, true);  // net2 in P1
    hipLaunchKernelGGL(to_ncdhw_kernel, blk(n24), dim3(BS), 0, stream, P1, out + (long)C * n48, n24);
    // 12 level
    down(P1, P0, m12, 9, 12, true);
    subm(P0, P1, m12, 10, 12, true);
    subm(P1, P0, m12, 11, 12, true);
    subm(P0, P1, m12, 12, 12, true);  // net3 in P1
    hipLaunchKernelGGL(to_ncdhw_kernel, blk(n12), dim3(BS), 0, stream, P1,
                       out + (long)C * (n48 + n24), n12);
    // 6 level
    down(P1, P0, m6, 13, 6, true);
    subm(P0, P1, m6, 14, 6, true);
    subm(P1, P0, m6, 15, 6, true);
    subm(P0, P1, m6, 16, 6, true);  // net4 in P1
    hipLaunchKernelGGL(to_ncdhw_kernel, blk(n6), dim3(BS), 0, stream, P1,
                       out + (long)C * (n48 + n24 + n12), n6);
}

// Round 5
// 2260.534 us; speedup vs baseline: 1.1265x; 1.1265x over previous
//
#include <hip/hip_runtime.h>

#define C 16
#define TAPS 27
#define NCONV 17
#define LISTCAP 131072

// ---- weight transpose: W[l][co][ci][tap] -> Wt[l][tap][ci][co] ----
__global__ void transpose_w_kernel(const float* __restrict__ W, float* __restrict__ Wt) {
    int i = blockIdx.x * blockDim.x + threadIdx.x;
    const int total = NCONV * TAPS * C * C;
    if (i >= total) return;
    int co = i & 15;
    int ci = (i >> 4) & 15;
    int rest = i >> 8;
    int tap = rest % TAPS;
    int l = rest / TAPS;
    Wt[i] = W[(((long)l * C + co) * C + ci) * TAPS + tap];
}

// ---- x: NCDHW -> NDHWC ----
__global__ void transpose_in_kernel(const float* __restrict__ x, float* __restrict__ xt, int n) {
    int v = blockIdx.x * blockDim.x + threadIdx.x;
    if (v >= n) return;
    float a[C];
#pragma unroll
    for (int ci = 0; ci < C; ci++) a[ci] = x[(long)ci * n + v];
    float4* dp = reinterpret_cast<float4*>(xt + (long)v * C);
    dp[0] = make_float4(a[0], a[1], a[2], a[3]);
    dp[1] = make_float4(a[4], a[5], a[6], a[7]);
    dp[2] = make_float4(a[8], a[9], a[10], a[11]);
    dp[3] = make_float4(a[12], a[13], a[14], a[15]);
}

// ---- NDHWC -> NCDHW (stage outputs into d_out) ----
__global__ void to_ncdhw_kernel(const float* __restrict__ src, float* __restrict__ dst, int n) {
    int v = blockIdx.x * blockDim.x + threadIdx.x;
    if (v >= n) return;
    const float4* sp = reinterpret_cast<const float4*>(src + (long)v * C);
    float4 q0 = sp[0], q1 = sp[1], q2 = sp[2], q3 = sp[3];
    dst[0L * n + v] = q0.x;  dst[1L * n + v] = q0.y;
    dst[2L * n + v] = q0.z;  dst[3L * n + v] = q0.w;
    dst[4L * n + v] = q1.x;  dst[5L * n + v] = q1.y;
    dst[6L * n + v] = q1.z;  dst[7L * n + v] = q1.w;
    dst[8L * n + v] = q2.x;  dst[9L * n + v] = q2.y;
    dst[10L * n + v] = q2.z; dst[11L * n + v] = q2.w;
    dst[12L * n + v] = q3.x; dst[13L * n + v] = q3.y;
    dst[14L * n + v] = q3.z; dst[15L * n + v] = q3.w;
}

// ---- ordered compaction: counts -> scan -> scatter ----
__global__ void count_kernel(const int* __restrict__ mi, int* __restrict__ counts, int n) {
    int i = blockIdx.x * 256 + threadIdx.x;
    int act = (i < n) && (mi[i] == 0);
    unsigned long long b = __ballot(act);
    __shared__ int wsum[4];
    int wid = threadIdx.x >> 6, lane = threadIdx.x & 63;
    if (lane == 0) wsum[wid] = __popcll(b);
    __syncthreads();
    if (threadIdx.x == 0) counts[blockIdx.x] = wsum[0] + wsum[1] + wsum[2] + wsum[3];
}

__global__ void scan_kernel(const int* __restrict__ counts, int* __restrict__ offsets,
                            int* __restrict__ nact, int nb) {
    __shared__ int s[256];
    int t = threadIdx.x;
    const int CH = (nb + 255) / 256;
    int base = t * CH, sum = 0;
    for (int j = 0; j < CH; j++)
        if (base + j < nb) sum += counts[base + j];
    s[t] = sum;
    __syncthreads();
    for (int off = 1; off < 256; off <<= 1) {
        int v = (t >= off) ? s[t - off] : 0;
        __syncthreads();
        s[t] += v;
        __syncthreads();
    }
    int run = s[t] - sum;  // exclusive base
    for (int j = 0; j < CH; j++) {
        if (base + j < nb) {
            offsets[base + j] = run;
            run += counts[base + j];
        }
    }
    if (t == 255) *nact = s[255];
}

__global__ void scatter_kernel(const int* __restrict__ mi, const int* __restrict__ offsets,
                               int* __restrict__ list, int n, int cap) {
    int i = blockIdx.x * 256 + threadIdx.x;
    int act = (i < n) && (mi[i] == 0);
    unsigned long long b = __ballot(act);
    __shared__ int wsum[4];
    int wid = threadIdx.x >> 6, lane = threadIdx.x & 63;
    if (lane == 0) wsum[wid] = __popcll(b);
    __syncthreads();
    int wbase = 0;
    for (int w = 0; w < wid; w++) wbase += wsum[w];
    int prefix = __popcll(b & ((1ull << lane) - 1));
    if (act) {
        int pos = offsets[blockIdx.x] + wbase + prefix;
        if (pos < cap) list[pos] = i;
    }
}

// ---- mask maxpool (2x2x2 stride, 3^3 window) ----
template <bool FROM_INT>
__global__ void pool_mask_kernel(const int* __restrict__ mi, const float* __restrict__ mf,
                                 float* __restrict__ mout, int Din, int Dout) {
    int i = blockIdx.x * blockDim.x + threadIdx.x;
    int n = Dout * Dout * Dout;
    if (i >= n) return;
    int x = i % Dout, y = (i / Dout) % Dout, z = i / (Dout * Dout);
    float v = 0.f;
    for (int kz = 0; kz < 3; kz++) {
        int zz = 2 * z - 1 + kz;
        if (zz < 0 || zz >= Din) continue;
        for (int ky = 0; ky < 3; ky++) {
            int yy = 2 * y - 1 + ky;
            if (yy < 0 || yy >= Din) continue;
            for (int kx = 0; kx < 3; kx++) {
                int xx = 2 * x - 1 + kx;
                if (xx < 0 || xx >= Din) continue;
                long idx = ((long)zz * Din + yy) * Din + xx;
                float mv = FROM_INT ? ((mi[idx] == 0) ? 1.f : 0.f) : mf[idx];
                v = fmaxf(v, mv);
            }
        }
    }
    mout[i] = v;
}

// ---- conv in NDHWC; 2 voxels/thread, all 16 output channels ----
// No runtime-indexed value arrays: named float4 regs + compile-time-ci macro.
#define FMA16(A0, A1, CI)                                        \
    {                                                            \
        const float* wr_ = wt + (CI) * C;                        \
        _Pragma("unroll") for (int co_ = 0; co_ < C; co_++) {    \
            float w_ = wr_[co_];                                 \
            acc0[co_] += (A0) * w_;                              \
            acc1[co_] += (A1) * w_;                              \
        }                                                        \
    }

template <int STRIDE, bool SPARSE>
__global__ __launch_bounds__(256) void conv_kernel(
    const float* __restrict__ in, float* __restrict__ out,
    const float* __restrict__ mask, const int* __restrict__ list,
    const int* __restrict__ nact, const float* __restrict__ Wt,
    const float* __restrict__ bs, const float* __restrict__ bb,
    int Din, int Dout) {
    int n = Dout * Dout * Dout;
    int nv = SPARSE ? *nact : n;
    if (SPARSE && nv > LISTCAP) nv = LISTCAP;
    if ((int)(blockIdx.x * 512) >= nv) return;  // uniform whole-block early exit

    __shared__ float wl[TAPS * C * C];
    __shared__ float sc[C], bi[C];
    int tid = threadIdx.x;
    for (int idx = tid; idx < TAPS * C * C; idx += 256) wl[idx] = Wt[idx];
    if (tid < C) { sc[tid] = bs[tid]; bi[tid] = bb[tid]; }
    __syncthreads();

    int s0 = blockIdx.x * 512 + tid;
    int s1 = s0 + 256;
    bool val0 = s0 < nv, val1 = s1 < nv;
    int v0 = 0, v1 = 0;
    if (SPARSE) {
        if (val0) v0 = list[s0];
        if (val1) v1 = list[s1];
    } else {
        v0 = val0 ? s0 : 0;
        v1 = val1 ? s1 : 0;
    }
    int x0 = v0 % Dout, y0 = (v0 / Dout) % Dout, z0 = v0 / (Dout * Dout);
    int x1 = v1 % Dout, y1 = (v1 / Dout) % Dout, z1 = v1 / (Dout * Dout);
    float mk0 = SPARSE ? 1.f : (val0 ? mask[v0] : 0.f);
    float mk1 = SPARSE ? 1.f : (val1 ? mask[v1] : 0.f);

    float acc0[C], acc1[C];
#pragma unroll
    for (int co = 0; co < C; co++) { acc0[co] = 0.f; acc1[co] = 0.f; }

    const float4 z4 = make_float4(0.f, 0.f, 0.f, 0.f);
    for (int kz = 0; kz < 3; kz++) {
        int zz0 = STRIDE * z0 - 1 + kz;
        int zz1 = STRIDE * z1 - 1 + kz;
        for (int ky = 0; ky < 3; ky++) {
            int yy0 = STRIDE * y0 - 1 + ky;
            int yy1 = STRIDE * y1 - 1 + ky;
#pragma unroll
            for (int kx = 0; kx < 3; kx++) {
                int xx0 = STRIDE * x0 - 1 + kx;
                int xx1 = STRIDE * x1 - 1 + kx;
                bool ok0 = ((unsigned)zz0 < (unsigned)Din) && ((unsigned)yy0 < (unsigned)Din) &&
                           ((unsigned)xx0 < (unsigned)Din);
                bool ok1 = ((unsigned)zz1 < (unsigned)Din) && ((unsigned)yy1 < (unsigned)Din) &&
                           ((unsigned)xx1 < (unsigned)Din);
                int b0 = ok0 ? ((zz0 * Din + yy0) * Din + xx0) : 0;
                int b1 = ok1 ? ((zz1 * Din + yy1) * Din + xx1) : 0;
                const float4* p0 = reinterpret_cast<const float4*>(in + (long)b0 * C);
                const float4* p1 = reinterpret_cast<const float4*>(in + (long)b1 * C);
                float4 a00 = p0[0], a01 = p0[1], a02 = p0[2], a03 = p0[3];
                float4 a10 = p1[0], a11 = p1[1], a12 = p1[2], a13 = p1[3];
                if (!ok0) { a00 = z4; a01 = z4; a02 = z4; a03 = z4; }
                if (!ok1) { a10 = z4; a11 = z4; a12 = z4; a13 = z4; }
                const float* wt = &wl[((kz * 3 + ky) * 3 + kx) * C * C];
                FMA16(a00.x, a10.x, 0)
                FMA16(a00.y, a10.y, 1)
                FMA16(a00.z, a10.z, 2)
                FMA16(a00.w, a10.w, 3)
                FMA16(a01.x, a11.x, 4)
                FMA16(a01.y, a11.y, 5)
                FMA16(a01.z, a11.z, 6)
                FMA16(a01.w, a11.w, 7)
                FMA16(a02.x, a12.x, 8)
                FMA16(a02.y, a12.y, 9)
                FMA16(a02.z, a12.z, 10)
                FMA16(a02.w, a12.w, 11)
                FMA16(a03.x, a13.x, 12)
                FMA16(a03.y, a13.y, 13)
                FMA16(a03.z, a13.z, 14)
                FMA16(a03.w, a13.w, 15)
            }
        }
    }

    float r0[C], r1[C];
#pragma unroll
    for (int co = 0; co < C; co++) {
        r0[co] = fmaxf(acc0[co] * sc[co] + bi[co], 0.f) * mk0;
        r1[co] = fmaxf(acc1[co] * sc[co] + bi[co], 0.f) * mk1;
    }
    if (val0) {
        float4* o4 = reinterpret_cast<float4*>(out + (long)v0 * C);
        o4[0] = make_float4(r0[0], r0[1], r0[2], r0[3]);
        o4[1] = make_float4(r0[4], r0[5], r0[6], r0[7]);
        o4[2] = make_float4(r0[8], r0[9], r0[10], r0[11]);
        o4[3] = make_float4(r0[12], r0[13], r0[14], r0[15]);
    }
    if (val1) {
        float4* o4 = reinterpret_cast<float4*>(out + (long)v1 * C);
        o4[0] = make_float4(r1[0], r1[1], r1[2], r1[3]);
        o4[1] = make_float4(r1[4], r1[5], r1[6], r1[7]);
        o4[2] = make_float4(r1[8], r1[9], r1[10], r1[11]);
        o4[3] = make_float4(r1[12], r1[13], r1[14], r1[15]);
    }
}

extern "C" void kernel_launch(void* const* d_in, const int* in_sizes, int n_in,
                              void* d_out, int out_size, void* d_ws, size_t ws_size,
                              hipStream_t stream) {
    const float* x = (const float*)d_in[0];
    const int* mask_idx = (const int*)d_in[1];
    const float* W = (const float*)d_in[2];
    const float* bs = (const float*)d_in[3];
    const float* bb = (const float*)d_in[4];
    float* out = (float*)d_out;
    float* ws = (float*)d_ws;

    const int n96 = 96 * 96 * 96;  // 884736
    const int n48 = 48 * 48 * 48;  // 110592
    const int n24 = 24 * 24 * 24;  // 13824
    const int n12 = 12 * 12 * 12;  // 1728
    const int n6 = 6 * 6 * 6;      // 216
    const int NB = (n96 + 255) / 256;  // 3456

    float* P0 = ws;                  // xt, then ping-pong
    float* P1 = P0 + (long)C * n96;  // ping-pong (pre-zeroed for sparse scatter)
    float* m48 = P1 + (long)C * n96;
    float* m24 = m48 + n48;
    float* m12 = m24 + n24;
    float* m6 = m12 + n12;
    float* Wt = m6 + n6;
    int* list = (int*)(Wt + (long)NCONV * TAPS * C * C);
    int* counts = list + LISTCAP;
    int* offsets = counts + NB;
    int* nact = offsets + NB;

    const int BS = 256;
    auto blk = [&](long t) { return dim3((unsigned)((t + BS - 1) / BS)); };

    hipMemsetAsync(P1, 0, (long)C * n96 * sizeof(float), stream);
    hipLaunchKernelGGL(transpose_w_kernel, blk(NCONV * TAPS * C * C), dim3(BS), 0, stream, W, Wt);
    hipLaunchKernelGGL(transpose_in_kernel, blk(n96), dim3(BS), 0, stream, x, P0, n96);
    hipLaunchKernelGGL(count_kernel, dim3(NB), dim3(BS), 0, stream, mask_idx, counts, n96);
    hipLaunchKernelGGL(scan_kernel, dim3(1), dim3(BS), 0, stream, counts, offsets, nact, NB);
    hipLaunchKernelGGL(scatter_kernel, dim3(NB), dim3(BS), 0, stream, mask_idx, offsets, list,
                       n96, LISTCAP);

    auto sconv = [&](const float* in, float* op, int layer) {
        hipLaunchKernelGGL((conv_kernel<1, true>), dim3(LISTCAP / 512), dim3(BS), 0, stream,
                           in, op, (const float*)nullptr, list, nact,
                           Wt + (long)layer * TAPS * C * C, bs + layer * C, bb + layer * C, 96, 96);
    };
    auto subm = [&](const float* in, float* op, const float* m, int layer, int D) {
        int n = D * D * D;
        hipLaunchKernelGGL((conv_kernel<1, false>), dim3((n + 511) / 512), dim3(BS), 0, stream,
                           in, op, m, list, nact, Wt + (long)layer * TAPS * C * C,
                           bs + layer * C, bb + layer * C, D, D);
    };
    auto down = [&](const float* in, float* op, const float* m, int layer, int Dout) {
        int n = Dout * Dout * Dout;
        hipLaunchKernelGGL((conv_kernel<2, false>), dim3((n + 511) / 512), dim3(BS), 0, stream,
                           in, op, m, list, nact, Wt + (long)layer * TAPS * C * C,
                           bs + layer * C, bb + layer * C, 2 * Dout, Dout);
    };

    // masks
    hipLaunchKernelGGL((pool_mask_kernel<true>), blk(n48), dim3(BS), 0, stream,
                       mask_idx, (const float*)nullptr, m48, 96, 48);
    hipLaunchKernelGGL((pool_mask_kernel<false>), blk(n24), dim3(BS), 0, stream,
                       (const int*)nullptr, m48, m24, 48, 24);
    hipLaunchKernelGGL((pool_mask_kernel<false>), blk(n12), dim3(BS), 0, stream,
                       (const int*)nullptr, m24, m12, 24, 12);
    hipLaunchKernelGGL((pool_mask_kernel<false>), blk(n6), dim3(BS), 0, stream,
                       (const int*)nullptr, m12, m6, 12, 6);

    // Stage @96 (sparse). L0: P0(xt) -> P1 (zeroed). L1: P1 -> P0 (inactive already 0 from x*mask).
    sconv(P0, P1, 0);
    sconv(P1, P0, 1);
    // 48 level (dense, ~94% mask)
    down(P0, P1, m48, 2, 48);
    subm(P1, P0, m48, 3, 48);
    subm(P0, P1, m48, 4, 48);  // net1 in P1
    hipLaunchKernelGGL(to_ncdhw_kernel, blk(n48), dim3(BS), 0, stream, P1, out, n48);
    // 24 level
    down(P1, P0, m24, 5, 24);
    subm(P0, P1, m24, 6, 24);
    subm(P1, P0, m24, 7, 24);
    subm(P0, P1, m24, 8, 24);  // net2 in P1
    hipLaunchKernelGGL(to_ncdhw_kernel, blk(n24), dim3(BS), 0, stream, P1, out + (long)C * n48, n24);
    // 12 level
    down(P1, P0, m12, 9, 12);
    subm(P0, P1, m12, 10, 12);
    subm(P1, P0, m12, 11, 12);
    subm(P0, P1, m12, 12, 12);  // net3 in P1
    hipLaunchKernelGGL(to_ncdhw_kernel, blk(n12), dim3(BS), 0, stream, P1,
                       out + (long)C * (n48 + n24), n12);
    // 6 level
    down(P1, P0, m6, 13, 6);
    subm(P0, P1, m6, 14, 6);
    subm(P1, P0, m6, 15, 6);
    subm(P0, P1, m6, 16, 6);  // net4 in P1
    hipLaunchKernelGGL(to_ncdhw_kernel, blk(n6), dim3(BS), 0, stream, P1,
                       out + (long)C * (n48 + n24 + n12), n6);
}

// Round 6
// 825.537 us; speedup vs baseline: 3.0846x; 2.7383x over previous
//
#include <hip/hip_runtime.h>

#define C 16
#define TAPS 27
#define NCONV 17
#define LISTCAP 131072

// ---- weight transpose: W[l][co][ci][tap] -> Wt[l][tap][ci][co] ----
__global__ void transpose_w_kernel(const float* __restrict__ W, float* __restrict__ Wt) {
    int i = blockIdx.x * blockDim.x + threadIdx.x;
    const int total = NCONV * TAPS * C * C;
    if (i >= total) return;
    int co = i & 15;
    int ci = (i >> 4) & 15;
    int rest = i >> 8;
    int tap = rest % TAPS;
    int l = rest / TAPS;
    Wt[i] = W[(((long)l * C + co) * C + ci) * TAPS + tap];
}

// ---- x: NCDHW -> NDHWC ----
__global__ void transpose_in_kernel(const float* __restrict__ x, float* __restrict__ xt, int n) {
    int v = blockIdx.x * blockDim.x + threadIdx.x;
    if (v >= n) return;
    float a[C];
#pragma unroll
    for (int ci = 0; ci < C; ci++) a[ci] = x[(long)ci * n + v];
    float4* dp = reinterpret_cast<float4*>(xt + (long)v * C);
    dp[0] = make_float4(a[0], a[1], a[2], a[3]);
    dp[1] = make_float4(a[4], a[5], a[6], a[7]);
    dp[2] = make_float4(a[8], a[9], a[10], a[11]);
    dp[3] = make_float4(a[12], a[13], a[14], a[15]);
}

// ---- NDHWC -> NCDHW (stage outputs into d_out) ----
__global__ void to_ncdhw_kernel(const float* __restrict__ src, float* __restrict__ dst, int n) {
    int v = blockIdx.x * blockDim.x + threadIdx.x;
    if (v >= n) return;
    const float4* sp = reinterpret_cast<const float4*>(src + (long)v * C);
    float4 q0 = sp[0], q1 = sp[1], q2 = sp[2], q3 = sp[3];
    dst[0L * n + v] = q0.x;  dst[1L * n + v] = q0.y;
    dst[2L * n + v] = q0.z;  dst[3L * n + v] = q0.w;
    dst[4L * n + v] = q1.x;  dst[5L * n + v] = q1.y;
    dst[6L * n + v] = q1.z;  dst[7L * n + v] = q1.w;
    dst[8L * n + v] = q2.x;  dst[9L * n + v] = q2.y;
    dst[10L * n + v] = q2.z; dst[11L * n + v] = q2.w;
    dst[12L * n + v] = q3.x; dst[13L * n + v] = q3.y;
    dst[14L * n + v] = q3.z; dst[15L * n + v] = q3.w;
}

// ---- ordered compaction: counts -> scan -> scatter ----
__global__ void count_kernel(const int* __restrict__ mi, int* __restrict__ counts, int n) {
    int i = blockIdx.x * 256 + threadIdx.x;
    int act = (i < n) && (mi[i] == 0);
    unsigned long long b = __ballot(act);
    __shared__ int wsum[4];
    int wid = threadIdx.x >> 6, lane = threadIdx.x & 63;
    if (lane == 0) wsum[wid] = __popcll(b);
    __syncthreads();
    if (threadIdx.x == 0) counts[blockIdx.x] = wsum[0] + wsum[1] + wsum[2] + wsum[3];
}

__global__ void scan_kernel(const int* __restrict__ counts, int* __restrict__ offsets,
                            int* __restrict__ nact, int nb) {
    __shared__ int s[256];
    int t = threadIdx.x;
    const int CH = (nb + 255) / 256;
    int base = t * CH, sum = 0;
    for (int j = 0; j < CH; j++)
        if (base + j < nb) sum += counts[base + j];
    s[t] = sum;
    __syncthreads();
    for (int off = 1; off < 256; off <<= 1) {
        int v = (t >= off) ? s[t - off] : 0;
        __syncthreads();
        s[t] += v;
        __syncthreads();
    }
    int run = s[t] - sum;  // exclusive base
    for (int j = 0; j < CH; j++) {
        if (base + j < nb) {
            offsets[base + j] = run;
            run += counts[base + j];
        }
    }
    if (t == 255) *nact = s[255];
}

__global__ void scatter_kernel(const int* __restrict__ mi, const int* __restrict__ offsets,
                               int* __restrict__ list, int n, int cap) {
    int i = blockIdx.x * 256 + threadIdx.x;
    int act = (i < n) && (mi[i] == 0);
    unsigned long long b = __ballot(act);
    __shared__ int wsum[4];
    int wid = threadIdx.x >> 6, lane = threadIdx.x & 63;
    if (lane == 0) wsum[wid] = __popcll(b);
    __syncthreads();
    int wbase = 0;
    for (int w = 0; w < wid; w++) wbase += wsum[w];
    int prefix = __popcll(b & ((1ull << lane) - 1));
    if (act) {
        int pos = offsets[blockIdx.x] + wbase + prefix;
        if (pos < cap) list[pos] = i;
    }
}

// ---- mask maxpool (2x2x2 stride, 3^3 window) ----
template <bool FROM_INT>
__global__ void pool_mask_kernel(const int* __restrict__ mi, const float* __restrict__ mf,
                                 float* __restrict__ mout, int Din, int Dout) {
    int i = blockIdx.x * blockDim.x + threadIdx.x;
    int n = Dout * Dout * Dout;
    if (i >= n) return;
    int x = i % Dout, y = (i / Dout) % Dout, z = i / (Dout * Dout);
    float v = 0.f;
    for (int kz = 0; kz < 3; kz++) {
        int zz = 2 * z - 1 + kz;
        if (zz < 0 || zz >= Din) continue;
        for (int ky = 0; ky < 3; ky++) {
            int yy = 2 * y - 1 + ky;
            if (yy < 0 || yy >= Din) continue;
            for (int kx = 0; kx < 3; kx++) {
                int xx = 2 * x - 1 + kx;
                if (xx < 0 || xx >= Din) continue;
                long idx = ((long)zz * Din + yy) * Din + xx;
                float mv = FROM_INT ? ((mi[idx] == 0) ? 1.f : 0.f) : mf[idx];
                v = fmaxf(v, mv);
            }
        }
    }
    mout[i] = v;
}

// ---- conv in NDHWC; 2 voxels/thread, all 16 output channels ----
// Spill-avoidance rules: accumulators indexed only by compile-time constants;
// at most TWO float4 load values live at any point (load->select->consume);
// kx loop NOT unrolled (small body, runtime tap index into LDS is fine).
#define FMA16(A0, A1, CI)                                     \
    {                                                         \
        const float* wr_ = wt + (CI) * C;                     \
        _Pragma("unroll") for (int co_ = 0; co_ < C; co_++) { \
            float w_ = wr_[co_];                              \
            acc0[co_] += (A0) * w_;                           \
            acc1[co_] += (A1) * w_;                           \
        }                                                     \
    }

template <int STRIDE, bool SPARSE>
__global__ __launch_bounds__(256) void conv_kernel(
    const float* __restrict__ in, float* __restrict__ out,
    const float* __restrict__ mask, const int* __restrict__ list,
    const int* __restrict__ nact, const float* __restrict__ Wt,
    const float* __restrict__ bs, const float* __restrict__ bb,
    int Din, int Dout) {
    int n = Dout * Dout * Dout;
    int nv = SPARSE ? *nact : n;
    if (SPARSE && nv > LISTCAP) nv = LISTCAP;
    if ((int)(blockIdx.x * 512) >= nv) return;  // uniform whole-block early exit

    __shared__ float wl[TAPS * C * C];
    __shared__ float sc[C], bi[C];
    int tid = threadIdx.x;
    for (int idx = tid; idx < TAPS * C * C; idx += 256) wl[idx] = Wt[idx];
    if (tid < C) { sc[tid] = bs[tid]; bi[tid] = bb[tid]; }
    __syncthreads();

    int s0 = blockIdx.x * 512 + tid;
    int s1 = s0 + 256;
    bool val0 = s0 < nv, val1 = s1 < nv;
    int v0 = 0, v1 = 0;
    if (SPARSE) {
        if (val0) v0 = list[s0];
        if (val1) v1 = list[s1];
    } else {
        v0 = val0 ? s0 : 0;
        v1 = val1 ? s1 : 0;
    }
    int x0 = v0 % Dout, y0 = (v0 / Dout) % Dout, z0 = v0 / (Dout * Dout);
    int x1 = v1 % Dout, y1 = (v1 / Dout) % Dout, z1 = v1 / (Dout * Dout);
    float mk0 = SPARSE ? 1.f : (val0 ? mask[v0] : 0.f);
    float mk1 = SPARSE ? 1.f : (val1 ? mask[v1] : 0.f);

    float acc0[C], acc1[C];
#pragma unroll
    for (int co = 0; co < C; co++) { acc0[co] = 0.f; acc1[co] = 0.f; }

    const float4 z4 = make_float4(0.f, 0.f, 0.f, 0.f);
    for (int kz = 0; kz < 3; kz++) {
        int zz0 = STRIDE * z0 - 1 + kz;
        int zz1 = STRIDE * z1 - 1 + kz;
        for (int ky = 0; ky < 3; ky++) {
            int yy0 = STRIDE * y0 - 1 + ky;
            int yy1 = STRIDE * y1 - 1 + ky;
            for (int kx = 0; kx < 3; kx++) {
                int xx0 = STRIDE * x0 - 1 + kx;
                int xx1 = STRIDE * x1 - 1 + kx;
                bool ok0 = ((unsigned)zz0 < (unsigned)Din) && ((unsigned)yy0 < (unsigned)Din) &&
                           ((unsigned)xx0 < (unsigned)Din);
                bool ok1 = ((unsigned)zz1 < (unsigned)Din) && ((unsigned)yy1 < (unsigned)Din) &&
                           ((unsigned)xx1 < (unsigned)Din);
                int b0 = ok0 ? ((zz0 * Din + yy0) * Din + xx0) : 0;
                int b1 = ok1 ? ((zz1 * Din + yy1) * Din + xx1) : 0;
                const float4* p0 = reinterpret_cast<const float4*>(in + (long)b0 * C);
                const float4* p1 = reinterpret_cast<const float4*>(in + (long)b1 * C);
                const float* wt = &wl[((kz * 3 + ky) * 3 + kx) * C * C];

                float4 t0, t1;
                t0 = p0[0]; t1 = p1[0];
                if (!ok0) t0 = z4;
                if (!ok1) t1 = z4;
                FMA16(t0.x, t1.x, 0)
                FMA16(t0.y, t1.y, 1)
                FMA16(t0.z, t1.z, 2)
                FMA16(t0.w, t1.w, 3)
                t0 = p0[1]; t1 = p1[1];
                if (!ok0) t0 = z4;
                if (!ok1) t1 = z4;
                FMA16(t0.x, t1.x, 4)
                FMA16(t0.y, t1.y, 5)
                FMA16(t0.z, t1.z, 6)
                FMA16(t0.w, t1.w, 7)
                t0 = p0[2]; t1 = p1[2];
                if (!ok0) t0 = z4;
                if (!ok1) t1 = z4;
                FMA16(t0.x, t1.x, 8)
                FMA16(t0.y, t1.y, 9)
                FMA16(t0.z, t1.z, 10)
                FMA16(t0.w, t1.w, 11)
                t0 = p0[3]; t1 = p1[3];
                if (!ok0) t0 = z4;
                if (!ok1) t1 = z4;
                FMA16(t0.x, t1.x, 12)
                FMA16(t0.y, t1.y, 13)
                FMA16(t0.z, t1.z, 14)
                FMA16(t0.w, t1.w, 15)
            }
        }
    }

    if (val0) {
        float r[4];
        float4* o4 = reinterpret_cast<float4*>(out + (long)v0 * C);
#pragma unroll
        for (int q = 0; q < 4; q++) {
#pragma unroll
            for (int j = 0; j < 4; j++) {
                int co = q * 4 + j;
                r[j] = fmaxf(acc0[co] * sc[co] + bi[co], 0.f) * mk0;
            }
            o4[q] = make_float4(r[0], r[1], r[2], r[3]);
        }
    }
    if (val1) {
        float r[4];
        float4* o4 = reinterpret_cast<float4*>(out + (long)v1 * C);
#pragma unroll
        for (int q = 0; q < 4; q++) {
#pragma unroll
            for (int j = 0; j < 4; j++) {
                int co = q * 4 + j;
                r[j] = fmaxf(acc1[co] * sc[co] + bi[co], 0.f) * mk1;
            }
            o4[q] = make_float4(r[0], r[1], r[2], r[3]);
        }
    }
}

extern "C" void kernel_launch(void* const* d_in, const int* in_sizes, int n_in,
                              void* d_out, int out_size, void* d_ws, size_t ws_size,
                              hipStream_t stream) {
    const float* x = (const float*)d_in[0];
    const int* mask_idx = (const int*)d_in[1];
    const float* W = (const float*)d_in[2];
    const float* bs = (const float*)d_in[3];
    const float* bb = (const float*)d_in[4];
    float* out = (float*)d_out;
    float* ws = (float*)d_ws;

    const int n96 = 96 * 96 * 96;  // 884736
    const int n48 = 48 * 48 * 48;  // 110592
    const int n24 = 24 * 24 * 24;  // 13824
    const int n12 = 12 * 12 * 12;  // 1728
    const int n6 = 6 * 6 * 6;      // 216
    const int NB = (n96 + 255) / 256;  // 3456

    float* P0 = ws;                  // xt, then ping-pong
    float* P1 = P0 + (long)C * n96;  // ping-pong (pre-zeroed for sparse scatter)
    float* m48 = P1 + (long)C * n96;
    float* m24 = m48 + n48;
    float* m12 = m24 + n24;
    float* m6 = m12 + n12;
    float* Wt = m6 + n6;
    int* list = (int*)(Wt + (long)NCONV * TAPS * C * C);
    int* counts = list + LISTCAP;
    int* offsets = counts + NB;
    int* nact = offsets + NB;

    const int BS = 256;
    auto blk = [&](long t) { return dim3((unsigned)((t + BS - 1) / BS)); };

    hipMemsetAsync(P1, 0, (long)C * n96 * sizeof(float), stream);
    hipLaunchKernelGGL(transpose_w_kernel, blk(NCONV * TAPS * C * C), dim3(BS), 0, stream, W, Wt);
    hipLaunchKernelGGL(transpose_in_kernel, blk(n96), dim3(BS), 0, stream, x, P0, n96);
    hipLaunchKernelGGL(count_kernel, dim3(NB), dim3(BS), 0, stream, mask_idx, counts, n96);
    hipLaunchKernelGGL(scan_kernel, dim3(1), dim3(BS), 0, stream, counts, offsets, nact, NB);
    hipLaunchKernelGGL(scatter_kernel, dim3(NB), dim3(BS), 0, stream, mask_idx, offsets, list,
                       n96, LISTCAP);

    auto sconv = [&](const float* in, float* op, int layer) {
        hipLaunchKernelGGL((conv_kernel<1, true>), dim3(LISTCAP / 512), dim3(BS), 0, stream,
                           in, op, (const float*)nullptr, list, nact,
                           Wt + (long)layer * TAPS * C * C, bs + layer * C, bb + layer * C, 96, 96);
    };
    auto subm = [&](const float* in, float* op, const float* m, int layer, int D) {
        int n = D * D * D;
        hipLaunchKernelGGL((conv_kernel<1, false>), dim3((n + 511) / 512), dim3(BS), 0, stream,
                           in, op, m, list, nact, Wt + (long)layer * TAPS * C * C,
                           bs + layer * C, bb + layer * C, D, D);
    };
    auto down = [&](const float* in, float* op, const float* m, int layer, int Dout) {
        int n = Dout * Dout * Dout;
        hipLaunchKernelGGL((conv_kernel<2, false>), dim3((n + 511) / 512), dim3(BS), 0, stream,
                           in, op, m, list, nact, Wt + (long)layer * TAPS * C * C,
                           bs + layer * C, bb + layer * C, 2 * Dout, Dout);
    };

    // masks
    hipLaunchKernelGGL((pool_mask_kernel<true>), blk(n48), dim3(BS), 0, stream,
                       mask_idx, (const float*)nullptr, m48, 96, 48);
    hipLaunchKernelGGL((pool_mask_kernel<false>), blk(n24), dim3(BS), 0, stream,
                       (const int*)nullptr, m48, m24, 48, 24);
    hipLaunchKernelGGL((pool_mask_kernel<false>), blk(n12), dim3(BS), 0, stream,
                       (const int*)nullptr, m24, m12, 24, 12);
    hipLaunchKernelGGL((pool_mask_kernel<false>), blk(n6), dim3(BS), 0, stream,
                       (const int*)nullptr, m12, m6, 12, 6);

    // Stage @96 (sparse). L0: P0(xt) -> P1 (zeroed). L1: P1 -> P0 (inactive already 0 from x*mask).
    sconv(P0, P1, 0);
    sconv(P1, P0, 1);
    // 48 level (dense, ~94% mask)
    down(P0, P1, m48, 2, 48);
    subm(P1, P0, m48, 3, 48);
    subm(P0, P1, m48, 4, 48);  // net1 in P1
    hipLaunchKernelGGL(to_ncdhw_kernel, blk(n48), dim3(BS), 0, stream, P1, out, n48);
    // 24 level
    down(P1, P0, m24, 5, 24);
    subm(P0, P1, m24, 6, 24);
    subm(P1, P0, m24, 7, 24);
    subm(P0, P1, m24, 8, 24);  // net2 in P1
    hipLaunchKernelGGL(to_ncdhw_kernel, blk(n24), dim3(BS), 0, stream, P1, out + (long)C * n48, n24);
    // 12 level
    down(P1, P0, m12, 9, 12);
    subm(P0, P1, m12, 10, 12);
    subm(P1, P0, m12, 11, 12);
    subm(P0, P1, m12, 12, 12);  // net3 in P1
    hipLaunchKernelGGL(to_ncdhw_kernel, blk(n12), dim3(BS), 0, stream, P1,
                       out + (long)C * (n48 + n24), n12);
    // 6 level
    down(P1, P0, m6, 13, 6);
    subm(P0, P1, m6, 14, 6);
    subm(P1, P0, m6, 15, 6);
    subm(P0, P1, m6, 16, 6);  // net4 in P1
    hipLaunchKernelGGL(to_ncdhw_kernel, blk(n6), dim3(BS), 0, stream, P1,
                       out + (long)C * (n48 + n24 + n12), n6);
}